// Round 11
// baseline (115.370 us; speedup 1.0000x reference)
//
#include <hip/hip_runtime.h>

#define E_EDGES 8192
#define N_COMP  20000
#define N_IND   500
#define NKEYS   512

typedef short bf16x8 __attribute__((ext_vector_type(8)));
typedef float f32x4  __attribute__((ext_vector_type(4)));

static __device__ __forceinline__ unsigned short f2bf(float v) {
    unsigned u = __builtin_bit_cast(unsigned, v);
    u = (u + 0x7FFFu + ((u >> 16) & 1u)) >> 16;
    return (unsigned short)u;
}

static __device__ __forceinline__ void cvt8(const float* __restrict__ s,
                                            unsigned short* __restrict__ d) {
    float4 a = *(const float4*)s;
    float4 b = *(const float4*)(s + 4);
    bf16x8 o;
    o[0] = (short)f2bf(a.x); o[1] = (short)f2bf(a.y);
    o[2] = (short)f2bf(a.z); o[3] = (short)f2bf(a.w);
    o[4] = (short)f2bf(b.x); o[5] = (short)f2bf(b.y);
    o[6] = (short)f2bf(b.z); o[7] = (short)f2bf(b.w);
    *(bf16x8*)d = o;
}

static __device__ __forceinline__ bf16x8 cvt8r(const float* __restrict__ s) {
    float4 a = *(const float4*)s;
    float4 b = *(const float4*)(s + 4);
    bf16x8 v;
    v[0] = (short)f2bf(a.x); v[1] = (short)f2bf(a.y);
    v[2] = (short)f2bf(a.z); v[3] = (short)f2bf(a.w);
    v[4] = (short)f2bf(b.x); v[5] = (short)f2bf(b.y);
    v[6] = (short)f2bf(b.z); v[7] = (short)f2bf(b.w);
    return v;
}

#define SWZ(r)   (((r) & 7) << 4)
#define SWZ4(r)  ((((r) >> 1) & 3) << 4)

static __device__ __forceinline__ void stage_f32(const float* src, char* base,
                                                 int sr, int sc) {
    *(bf16x8*)(base + ((sr * 64 + sc * 2) ^ SWZ(sr))) = cvt8r(src);
}

// ---------------------------------------------------------------------------
// prep: block-range-dispatched preprocessing (unchanged).
// ---------------------------------------------------------------------------
__global__ __launch_bounds__(256) void prep(
    const int* __restrict__ src, const int* __restrict__ tgt,
    const float* __restrict__ Wc, const float* __restrict__ Wi,
    const float* __restrict__ w_out, const float* __restrict__ w_in,
    const float* __restrict__ bc, const float* __restrict__ bi,
    const float* __restrict__ b_in,
    float* __restrict__ csrc, float* __restrict__ ctgt,
    unsigned short* __restrict__ Wc_bf, unsigned short* __restrict__ wout_bf,
    unsigned short* __restrict__ WcT_bf, unsigned short* __restrict__ Wi_bf,
    unsigned short* __restrict__ wkv_bf, float* __restrict__ beff)
{
    const int bid = blockIdx.x, tid = threadIdx.x;
    if (bid < 32) {
        int e = bid * 256 + tid;
        atomicAdd(&csrc[src[e]], 1.0f);
        atomicAdd(&ctgt[tgt[e]], 1.0f);
    } else if (bid < 64) {
        long i = ((long)(bid - 32) * 256 + tid) * 8;
        cvt8(Wc + i, Wc_bf + i);
    } else if (bid < 96) {
        long i = ((long)(bid - 64) * 256 + tid) * 8;
        cvt8(w_out + i, wout_bf + i);
    } else if (bid < 128) {
        long o = ((long)(bid - 96) * 256 + tid) * 8;
        int c = (int)(o >> 8), d0 = (int)(o & 255);
        bf16x8 v;
#pragma unroll
        for (int j = 0; j < 8; j++) v[j] = (short)f2bf(Wc[(long)(d0 + j) * 256 + c]);
        *(bf16x8*)(WcT_bf + o) = v;
    } else if (bid < 144) {
        long i = ((long)(bid - 128) * 256 + tid) * 8;
        cvt8(Wi + i, Wi_bf + i);
    } else if (bid < 208) {
        long i = ((long)(bid - 144) * 256 + tid) * 8;
        cvt8(w_in + 65536 + i, wkv_bf + i);
    } else {
        int gi = (bid - 208) * 256 + tid;      // [0, 3072)
        int e = gi >> 2, q = gi & 3;
        const float* base = (e < 256) ? bc : bi;
        const float* wr = w_in + (long)e * 256 + q * 64;
        const float* br = base + q * 64;
        float s = 0.f;
#pragma unroll
        for (int j = 0; j < 64; j += 4) {
            float4 w4 = *(const float4*)(wr + j);
            float4 b4 = *(const float4*)(br + j);
            s += w4.x * b4.x + w4.y * b4.y + w4.z * b4.z + w4.w * b4.w;
        }
        s += __shfl_xor(s, 1);
        s += __shfl_xor(s, 2);
        if (q == 0) beff[e] = s + b_in[e];
    }
}

// ---------------------------------------------------------------------------
// fusedW (LDS-staged; unchanged).
// ---------------------------------------------------------------------------
__global__ __launch_bounds__(256) void fusedW(
    const float* __restrict__ w_in, const unsigned short* __restrict__ WcT_bf,
    const float* __restrict__ industry_x, const unsigned short* __restrict__ Wi_bf,
    const unsigned short* __restrict__ wkv_bf, const float* __restrict__ beff,
    const float* __restrict__ ctgt, const float* __restrict__ csrc,
    unsigned short* __restrict__ Wcq_bf, unsigned short* __restrict__ Kbuf,
    unsigned short* __restrict__ VTg,
    float* __restrict__ cntT, int* __restrict__ list, int* __restrict__ nlist)
{
    const int bid = blockIdx.x;
    if (bid >= 20) {
        int i = (bid - 20) * 256 + threadIdx.x;
        if (i < NKEYS) cntT[(i & 15) * 32 + (i >> 4)] = ctgt[i];
        if (i < N_COMP && csrc[i] > 0.f) {
            int k = atomicAdd(nlist, 1);
            list[k] = i;
        }
        return;
    }

    __shared__ char lds[48 * 1024];
    const int t = threadIdx.x, wv = t >> 6, lane = t & 63;
    const int g = lane >> 4, ln = lane & 15;
    const int sr = t >> 2, sc = (t & 3) * 8;

    if (bid < 4) {
        char* ab = lds;
        char* wb = lds + 4 * 1024;
        const int bm = bid * 64;
        f32x4 acc[16];
#pragma unroll
        for (int i = 0; i < 16; i++) acc[i] = (f32x4){0.f, 0.f, 0.f, 0.f};
        const float* aptr = w_in + (long)(bm + sr) * 256 + sc;
        for (int kc = 0; kc < 256; kc += 32) {
            __syncthreads();
            stage_f32(aptr + kc, ab, sr, sc);
#pragma unroll
            for (int p = 0; p < 4; p++) {
                int r = p * 64 + sr;
                *(bf16x8*)(wb + ((r * 64 + sc * 2) ^ SWZ(r))) =
                    *(const bf16x8*)(WcT_bf + (long)r * 256 + kc + sc);
            }
            __syncthreads();
            int ar = wv * 16 + ln;
            bf16x8 af = *(bf16x8*)(ab + ((ar * 64 + g * 16) ^ SWZ(ar)));
#pragma unroll
            for (int nj = 0; nj < 16; nj++) {
                int wr = nj * 16 + ln;
                bf16x8 bf = *(bf16x8*)(wb + ((wr * 64 + g * 16) ^ SWZ(wr)));
                acc[nj] = __builtin_amdgcn_mfma_f32_16x16x32_bf16(af, bf, acc[nj], 0, 0, 0);
            }
        }
#pragma unroll
        for (int nj = 0; nj < 16; nj++)
#pragma unroll
            for (int r = 0; r < 4; r++)
                Wcq_bf[(long)(bm + wv * 16 + g * 4 + r) * 256 + nj * 16 + ln] =
                    f2bf(acc[nj][r]);
        return;
    }

    const int rg = (bid - 4) >> 1, colh = (bid - 4) & 1;
    char* ab  = lds;
    char* wb1 = lds + 4 * 1024;
    char* ihb = lds + 16 * 1024;
    char* wb2 = lds;

    {
        f32x4 a1[16];
#pragma unroll
        for (int i = 0; i < 16; i++) a1[i] = (f32x4){0.f, 0.f, 0.f, 0.f};
        int arow = rg * 64 + sr; if (arow > N_IND - 1) arow = N_IND - 1;
        const float* aptr = industry_x + (long)arow * 128 + sc;
        for (int kc = 0; kc < 128; kc += 32) {
            __syncthreads();
            stage_f32(aptr + kc, ab, sr, sc);
#pragma unroll
            for (int p = 0; p < 4; p++) {
                int r = p * 64 + sr;
                *(bf16x8*)(wb1 + ((r * 64 + sc * 2) ^ SWZ(r))) =
                    *(const bf16x8*)(Wi_bf + (long)r * 128 + kc + sc);
            }
            __syncthreads();
            int ar = wv * 16 + ln;
            bf16x8 af = *(bf16x8*)(ab + ((ar * 64 + g * 16) ^ SWZ(ar)));
#pragma unroll
            for (int nj = 0; nj < 16; nj++) {
                int wr = nj * 16 + ln;
                bf16x8 bf = *(bf16x8*)(wb1 + ((wr * 64 + g * 16) ^ SWZ(wr)));
                a1[nj] = __builtin_amdgcn_mfma_f32_16x16x32_bf16(af, bf, a1[nj], 0, 0, 0);
            }
        }
        __syncthreads();
#pragma unroll
        for (int nj = 0; nj < 16; nj++)
#pragma unroll
            for (int r = 0; r < 4; r++) {
                int row = wv * 16 + g * 4 + r, col = nj * 16 + ln;
                *(unsigned short*)(ihb + ((row * 512 + col * 2) ^ SWZ(row))) =
                    f2bf(a1[nj][r]);
            }
    }
    __syncthreads();

    if (colh == 0) {
        f32x4 a2[16];
#pragma unroll
        for (int i = 0; i < 16; i++) a2[i] = (f32x4){0.f, 0.f, 0.f, 0.f};
        for (int kc = 0; kc < 256; kc += 32) {
            __syncthreads();
#pragma unroll
            for (int p = 0; p < 4; p++) {
                int r = p * 64 + sr;
                *(bf16x8*)(wb2 + ((r * 64 + sc * 2) ^ SWZ(r))) =
                    *(const bf16x8*)(wkv_bf + (long)r * 256 + kc + sc);
            }
            __syncthreads();
            int row = wv * 16 + ln;
            bf16x8 af = *(bf16x8*)(ihb + ((row * 512 + (kc + g * 8) * 2) ^ SWZ(row)));
#pragma unroll
            for (int nj = 0; nj < 16; nj++) {
                int wr = nj * 16 + ln;
                bf16x8 bf = *(bf16x8*)(wb2 + ((wr * 64 + g * 16) ^ SWZ(wr)));
                a2[nj] = __builtin_amdgcn_mfma_f32_16x16x32_bf16(af, bf, a2[nj], 0, 0, 0);
            }
        }
#pragma unroll
        for (int nj = 0; nj < 16; nj++)
#pragma unroll
            for (int r = 0; r < 4; r++) {
                int R = rg * 64 + wv * 16 + g * 4 + r, n = nj * 16 + ln;
                Kbuf[(long)R * 256 + n] = f2bf(a2[nj][r] + beff[256 + n]);
            }
    } else {
        const unsigned short* wp = wkv_bf + 65536;
        f32x4 a2[16];
#pragma unroll
        for (int i = 0; i < 16; i++) a2[i] = (f32x4){0.f, 0.f, 0.f, 0.f};
        for (int kc = 0; kc < 256; kc += 32) {
            __syncthreads();
#pragma unroll
            for (int p = 0; p < 4; p++) {
                int r = p * 64 + sr;
                *(bf16x8*)(wb2 + ((r * 64 + sc * 2) ^ SWZ(r))) =
                    *(const bf16x8*)(wp + (long)r * 256 + kc + sc);
            }
            __syncthreads();
#pragma unroll
            for (int mi = 0; mi < 4; mi++) {
                int arow = wv * 64 + mi * 16 + ln;
                bf16x8 af = *(bf16x8*)(wb2 + ((arow * 64 + g * 16) ^ SWZ(arow)));
#pragma unroll
                for (int t4 = 0; t4 < 4; t4++) {
                    int brow = t4 * 16 + ln;
                    bf16x8 bfr = *(bf16x8*)(ihb + ((brow * 512 + (kc + g * 8) * 2) ^ SWZ(brow)));
                    a2[mi * 4 + t4] = __builtin_amdgcn_mfma_f32_16x16x32_bf16(af, bfr, a2[mi * 4 + t4], 0, 0, 0);
                }
            }
        }
#pragma unroll
        for (int mi = 0; mi < 4; mi++)
#pragma unroll
            for (int t4 = 0; t4 < 4; t4++)
#pragma unroll
                for (int r = 0; r < 4; r++) {
                    int nrow = wv * 64 + mi * 16 + g * 4 + r;
                    VTg[(long)nrow * 512 + rg * 64 + t4 * 16 + ln] =
                        f2bf(a2[mi * 4 + t4][r] + beff[512 + nrow]);
                }
    }
}

// ---------------------------------------------------------------------------
// megattn v6: 16 rows/block, 512 threads = 8 waves. Wave (h, ks) = head h,
// keys [256ks, 256ks+256). Per-wave: S[8][2] regs, one shfl-reduce softmax,
// PV via wave-private LDS. Log-sum-exp merge of the two key-halves per head
// (exact), then 8-way split out-projection. VGPR capped at 128 -> up to
// 16 waves/CU.
// ---------------------------------------------------------------------------
__global__ __launch_bounds__(512, 4) void megattn(
    const float* __restrict__ company_x,
    const unsigned short* __restrict__ Wcq,
    const float* __restrict__ beff,
    const unsigned short* __restrict__ Kbuf,
    const unsigned short* __restrict__ VTg,
    const float* __restrict__ cntT,
    const unsigned short* __restrict__ wout,
    const float* __restrict__ b_out,
    const int* __restrict__ list, const int* __restrict__ nlist,
    float* __restrict__ pooled)
{
    const int M = *nlist;
    const int bm = blockIdx.x * 16;
    if (bm >= M) return;

    __shared__ char lds[57344];
    const int t = threadIdx.x;
    const int w = t >> 6;            // wave 0..7
    const int h = w & 3;             // head
    const int ks = w >> 2;           // key-split half
    const int lane = t & 63, g = lane >> 4, ln = lane & 15;

    char* qbase = lds + h * 2048;              // [16][64] bf16 ctx per head
    char* xbase = lds + 8192;                  // [16][256] bf16
    char* pbase = lds + 16384 + w * 2048;      // wave-private scratch (q-conv + P dbuf)
    float* macc = (float*)(lds + 32768) + h * 1024;  // [16][64] f32 per head
    float* mml  = (float*)(lds + 49152) + h * 512;   // [8][64] f32 per head

    // ---- 1. stage x (512 threads x 8 bf16 = 16x256) ----
    {
        int row = t >> 5, c0 = (t & 31) * 8;
        int mr = bm + row; if (mr > M - 1) mr = M - 1;
        const float* src = company_x + (long)list[mr] * 256 + c0;
        *(bf16x8*)(xbase + ((row * 512 + c0 * 2) ^ SWZ(row))) = cvt8r(src);
    }
    __syncthreads();

    // ---- 2. Q for head h (both ks waves duplicate; wave-private conversion) ----
    bf16x8 qf0, qf1;
    {
        f32x4 qa[4];
#pragma unroll
        for (int i = 0; i < 4; i++) qa[i] = (f32x4){0.f, 0.f, 0.f, 0.f};
#pragma unroll
        for (int kc = 0; kc < 256; kc += 32) {
            bf16x8 af = *(bf16x8*)(xbase + ((ln * 512 + (kc + g * 8) * 2) ^ SWZ(ln)));
#pragma unroll
            for (int nj = 0; nj < 4; nj++) {
                bf16x8 bf = *(const bf16x8*)(Wcq + (long)(h * 64 + nj * 16 + ln) * 256 + kc + g * 8);
                qa[nj] = __builtin_amdgcn_mfma_f32_16x16x32_bf16(af, bf, qa[nj], 0, 0, 0);
            }
        }
#pragma unroll
        for (int nj = 0; nj < 4; nj++)
#pragma unroll
            for (int r = 0; r < 4; r++) {
                int row = g * 4 + r, col = nj * 16 + ln;
                *(unsigned short*)(pbase + ((row * 128 + col * 2) ^ SWZ(row))) =
                    f2bf((qa[nj][r] + beff[h * 64 + col]) * 0.125f);
            }
        qf0 = *(bf16x8*)(pbase + ((ln * 128 + g * 16) ^ SWZ(ln)));
        qf1 = *(bf16x8*)(pbase + ((ln * 128 + 64 + g * 16) ^ SWZ(ln)));
    }

    // ---- 3a. QK^T over this wave's 256 keys (32 independent loads) ----
    f32x4 S[8][2];
#pragma unroll
    for (int c = 0; c < 8; c++)
#pragma unroll
        for (int sub = 0; sub < 2; sub++) {
            const unsigned short* kr =
                Kbuf + (long)(ks * 256 + c * 32 + sub * 16 + ln) * 256 + h * 64 + g * 8;
            bf16x8 k0 = *(const bf16x8*)(kr);
            bf16x8 k1 = *(const bf16x8*)(kr + 32);
            f32x4 s = (f32x4){0.f, 0.f, 0.f, 0.f};
            s = __builtin_amdgcn_mfma_f32_16x16x32_bf16(qf0, k0, s, 0, 0, 0);
            s = __builtin_amdgcn_mfma_f32_16x16x32_bf16(qf1, k1, s, 0, 0, 0);
            S[c][sub] = s;
        }

    // ---- 3b. counts for this half ----
    float cnt[16];
    {
        const float* cp = cntT + ln * 32 + ks * 16;
#pragma unroll
        for (int j4 = 0; j4 < 4; j4++) {
            float4 c4 = *(const float4*)(cp + j4 * 4);
            cnt[j4 * 4 + 0] = c4.x; cnt[j4 * 4 + 1] = c4.y;
            cnt[j4 * 4 + 2] = c4.z; cnt[j4 * 4 + 3] = c4.w;
        }
    }

    // ---- 3c. single-pass softmax over 256 keys ----
    float tm[4] = {-1e30f, -1e30f, -1e30f, -1e30f};
#pragma unroll
    for (int c = 0; c < 8; c++)
#pragma unroll
        for (int sub = 0; sub < 2; sub++)
#pragma unroll
            for (int r = 0; r < 4; r++) tm[r] = fmaxf(tm[r], S[c][sub][r]);
#pragma unroll
    for (int st = 1; st < 16; st <<= 1)
#pragma unroll
        for (int r = 0; r < 4; r++) tm[r] = fmaxf(tm[r], __shfl_xor(tm[r], st));

    float ps[4] = {0.f, 0.f, 0.f, 0.f};
#pragma unroll
    for (int c = 0; c < 8; c++)
#pragma unroll
        for (int sub = 0; sub < 2; sub++) {
            float cv = cnt[c * 2 + sub];
#pragma unroll
            for (int r = 0; r < 4; r++) {
                float p = cv * __expf(S[c][sub][r] - tm[r]);
                S[c][sub][r] = p;
                ps[r] += p;
            }
        }
#pragma unroll
    for (int st = 1; st < 16; st <<= 1)
#pragma unroll
        for (int r = 0; r < 4; r++) ps[r] += __shfl_xor(ps[r], st);

    // ---- 3d. PV over 8 chunks (wave-private double-buffered P LDS) ----
    f32x4 acc[4];
#pragma unroll
    for (int i = 0; i < 4; i++) acc[i] = (f32x4){0.f, 0.f, 0.f, 0.f};
#pragma unroll
    for (int c = 0; c < 8; c++) {
        char* pb = pbase + (c & 1) * 1024;
#pragma unroll
        for (int sub = 0; sub < 2; sub++)
#pragma unroll
            for (int r = 0; r < 4; r++) {
                int row = g * 4 + r;
                *(unsigned short*)(pb + ((row * 64 + (sub * 16 + ln) * 2) ^ SWZ4(row))) =
                    f2bf(S[c][sub][r]);
            }
        bf16x8 pa = *(bf16x8*)(pb + ((ln * 64 + g * 16) ^ SWZ4(ln)));
#pragma unroll
        for (int t4 = 0; t4 < 4; t4++) {
            bf16x8 vf = *(const bf16x8*)(
                VTg + (long)(h * 64 + t4 * 16 + ln) * 512 + ks * 256 + c * 32 + g * 8);
            acc[t4] = __builtin_amdgcn_mfma_f32_16x16x32_bf16(pa, vf, acc[t4], 0, 0, 0);
        }
    }

    // ---- 4. merge the two key-halves per head (exact log-sum-exp) ----
    if (ks == 1) {
#pragma unroll
        for (int t4 = 0; t4 < 4; t4++)
#pragma unroll
            for (int r = 0; r < 4; r++)
                macc[(t4 * 4 + r) * 64 + lane] = acc[t4][r];
#pragma unroll
        for (int r = 0; r < 4; r++) {
            mml[r * 64 + lane] = tm[r];
            mml[(4 + r) * 64 + lane] = ps[r];
        }
    }
    __syncthreads();
    if (ks == 0) {
        float sc0[4], sc1[4];
#pragma unroll
        for (int r = 0; r < 4; r++) {
            float m1 = mml[r * 64 + lane];
            float l1 = mml[(4 + r) * 64 + lane];
            float mn = fmaxf(tm[r], m1);
            float c0 = __expf(tm[r] - mn);
            float c1 = __expf(m1 - mn);
            float inv = 1.0f / (ps[r] * c0 + l1 * c1);
            sc0[r] = c0 * inv;
            sc1[r] = c1 * inv;
        }
#pragma unroll
        for (int t4 = 0; t4 < 4; t4++)
#pragma unroll
            for (int r = 0; r < 4; r++) {
                float ctxv = acc[t4][r] * sc0[r] + macc[(t4 * 4 + r) * 64 + lane] * sc1[r];
                int row = g * 4 + r, col = t4 * 16 + ln;
                *(unsigned short*)(qbase + ((row * 128 + col * 2) ^ SWZ(row))) =
                    f2bf(ctxv);
            }
    }
    __syncthreads();

    // ---- 5. out-proj: wave w handles cols [32w, 32w+32) ----
    {
        f32x4 oa[2];
#pragma unroll
        for (int i = 0; i < 2; i++) oa[i] = (f32x4){0.f, 0.f, 0.f, 0.f};
#pragma unroll
        for (int kc = 0; kc < 256; kc += 32) {
            int hs = kc >> 6;
            int off = (kc & 63) + g * 8;
            bf16x8 af = *(bf16x8*)(lds + hs * 2048 + ((ln * 128 + off * 2) ^ SWZ(ln)));
#pragma unroll
            for (int nj = 0; nj < 2; nj++) {
                int n = w * 32 + nj * 16 + ln;
                bf16x8 bf = *(const bf16x8*)(wout + (long)n * 256 + kc + g * 8);
                oa[nj] = __builtin_amdgcn_mfma_f32_16x16x32_bf16(af, bf, oa[nj], 0, 0, 0);
            }
        }
#pragma unroll
        for (int nj = 0; nj < 2; nj++) {
            int n = w * 32 + nj * 16 + ln;
            float bv = b_out[n];
#pragma unroll
            for (int r = 0; r < 4; r++) {
                int R = bm + g * 4 + r;
                if (R < M)
                    pooled[(long)list[R] * 256 + n] = oa[nj][r] + bv;
            }
        }
    }
}

// ---------------------------------------------------------------------------
// gemm_ln (LDS-staged; unchanged).
// ---------------------------------------------------------------------------
__global__ __launch_bounds__(256) void gemm_ln(
    const float* __restrict__ A, const unsigned short* __restrict__ W,
    const float* __restrict__ bias,
    const float* __restrict__ pooled, const float* __restrict__ csrc,
    const float* __restrict__ gamma, const float* __restrict__ beta,
    float* __restrict__ out, int M, int K)
{
    __shared__ unsigned short As[64 * 32];
    __shared__ unsigned short Ws[256 * 32];
    char* abase = (char*)As;
    char* wbase = (char*)Ws;

    const int bm = blockIdx.x * 64;
    const int t = threadIdx.x;
    const int wv = t >> 6, lane = t & 63, g = lane >> 4, ln = lane & 15;

    f32x4 acc[16];
#pragma unroll
    for (int i = 0; i < 16; i++) acc[i] = (f32x4){0.f, 0.f, 0.f, 0.f};

    const int sr = t >> 2;
    const int sc = (t & 3) * 8;
    int arow = bm + sr; if (arow > M - 1) arow = M - 1;
    const float* aptr = A + (long)arow * K + sc;

    for (int kc = 0; kc < K; kc += 32) {
        __syncthreads();
        stage_f32(aptr + kc, abase, sr, sc);
#pragma unroll
        for (int p = 0; p < 4; p++) {
            int r = p * 64 + sr;
            *(bf16x8*)(wbase + ((r * 64 + sc * 2) ^ SWZ(r))) =
                *(const bf16x8*)(W + (long)r * K + kc + sc);
        }
        __syncthreads();

        const int ar = wv * 16 + ln;
        bf16x8 af = *(bf16x8*)(abase + ((ar * 64 + g * 16) ^ SWZ(ar)));
#pragma unroll
        for (int nj = 0; nj < 16; nj++) {
            int wr = nj * 16 + ln;
            bf16x8 bf = *(bf16x8*)(wbase + ((wr * 64 + g * 16) ^ SWZ(wr)));
            acc[nj] = __builtin_amdgcn_mfma_f32_16x16x32_bf16(af, bf, acc[nj], 0, 0, 0);
        }
    }

#pragma unroll
    for (int r = 0; r < 4; r++) {
        int R = bm + wv * 16 + g * 4 + r;
        bool valid = R < M;
        int Rc = valid ? R : 0;
        float cntv = csrc[Rc];
        float factor = (valid && cntv > 0.f) ? cntv / (cntv + 1e-6f) : 0.f;

        float v[16];
        float sum = 0.f, sq = 0.f;
#pragma unroll
        for (int nj = 0; nj < 16; nj++) {
            int n = nj * 16 + ln;
            float x = acc[nj][r] + bias[n] + factor * pooled[(long)Rc * 256 + n];
            v[nj] = x;
            sum += x;
            sq  += x * x;
        }
#pragma unroll
        for (int st = 1; st < 16; st <<= 1) {
            sum += __shfl_xor(sum, st);
            sq  += __shfl_xor(sq,  st);
        }
        float mean = sum * (1.0f / 256.0f);
        float var  = sq * (1.0f / 256.0f) - mean * mean;
        float rstd = rsqrtf(var + 1e-5f);
        if (valid) {
#pragma unroll
            for (int nj = 0; nj < 16; nj++) {
                int n = nj * 16 + ln;
                out[(long)R * 256 + n] = (v[nj] - mean) * rstd * gamma[n] + beta[n];
            }
        }
    }
}

// ---------------------------------------------------------------------------
extern "C" void kernel_launch(void* const* d_in, const int* in_sizes, int n_in,
                              void* d_out, int out_size, void* d_ws, size_t ws_size,
                              hipStream_t stream)
{
    const float* company_x  = (const float*)d_in[0];
    const float* industry_x = (const float*)d_in[1];
    const int*   edge       = (const int*)d_in[2];
    const float* Wc         = (const float*)d_in[3];
    const float* bc         = (const float*)d_in[4];
    const float* Wi         = (const float*)d_in[5];
    const float* bi         = (const float*)d_in[6];
    const float* w_in       = (const float*)d_in[7];
    const float* b_in       = (const float*)d_in[8];
    const float* w_out      = (const float*)d_in[9];
    const float* b_out      = (const float*)d_in[10];
    const float* gamma      = (const float*)d_in[11];
    const float* beta       = (const float*)d_in[12];
    float* out = (float*)d_out;

    const int* src = edge;
    const int* tgt = edge + E_EDGES;

    // workspace carve (float units)
    float* wf = (float*)d_ws;
    size_t o = 0;
    unsigned short* Wc_bf   = (unsigned short*)(wf + o); o += 32768;  // 256x256
    unsigned short* wout_bf = (unsigned short*)(wf + o); o += 32768;
    unsigned short* WcT_bf  = (unsigned short*)(wf + o); o += 32768;
    unsigned short* Wi_bf   = (unsigned short*)(wf + o); o += 16384;  // 256x128
    unsigned short* wkv_bf  = (unsigned short*)(wf + o); o += 65536;  // 512x256
    unsigned short* Wcq_bf  = (unsigned short*)(wf + o); o += 32768;
    unsigned short* Kbuf    = (unsigned short*)(wf + o); o += 65536;  // 512x256
    unsigned short* VTg     = (unsigned short*)(wf + o); o += 65536;  // 256x512
    float* pooled           = wf + o; o += (size_t)N_COMP * 256;
    float* beff             = wf + o; o += 768;
    float* cntT             = wf + o; o += NKEYS;
    int*   list             = (int*)(wf + o); o += E_EDGES;
    // contiguous zeroed region: csrc | ctgt | nlist
    float* csrc             = wf + o; o += N_COMP;
    float* ctgt             = wf + o; o += NKEYS;
    int*   nlist            = (int*)(wf + o); o += 4;

    hipMemsetAsync(csrc, 0, (N_COMP + NKEYS + 4) * sizeof(float), stream);

    prep<<<dim3(220), dim3(256), 0, stream>>>(
        src, tgt, Wc, Wi, w_out, w_in, bc, bi, b_in,
        csrc, ctgt, Wc_bf, wout_bf, WcT_bf, Wi_bf, wkv_bf, beff);

    fusedW<<<dim3(99), dim3(256), 0, stream>>>(
        w_in, WcT_bf, industry_x, Wi_bf, wkv_bf, beff, ctgt, csrc,
        Wcq_bf, Kbuf, VTg, cntT, list, nlist);

    megattn<<<dim3(E_EDGES / 16), dim3(512), 0, stream>>>(
        company_x, Wcq_bf, beff, Kbuf, VTg, cntT, wout_bf, b_out,
        list, nlist, pooled);

    gemm_ln<<<dim3((N_COMP + 63) / 64), dim3(256), 0, stream>>>(
        company_x, Wc_bf, bc, pooled, csrc, gamma, beta, out, N_COMP, 256);
}

// Round 12
// 113.996 us; speedup vs baseline: 1.0121x; 1.0121x over previous
//
#include <hip/hip_runtime.h>

#define E_EDGES 8192
#define N_COMP  20000
#define N_IND   500
#define NKEYS   512

typedef short bf16x8 __attribute__((ext_vector_type(8)));
typedef float f32x4  __attribute__((ext_vector_type(4)));

static __device__ __forceinline__ unsigned short f2bf(float v) {
    unsigned u = __builtin_bit_cast(unsigned, v);
    u = (u + 0x7FFFu + ((u >> 16) & 1u)) >> 16;
    return (unsigned short)u;
}

static __device__ __forceinline__ void cvt8(const float* __restrict__ s,
                                            unsigned short* __restrict__ d) {
    float4 a = *(const float4*)s;
    float4 b = *(const float4*)(s + 4);
    bf16x8 o;
    o[0] = (short)f2bf(a.x); o[1] = (short)f2bf(a.y);
    o[2] = (short)f2bf(a.z); o[3] = (short)f2bf(a.w);
    o[4] = (short)f2bf(b.x); o[5] = (short)f2bf(b.y);
    o[6] = (short)f2bf(b.z); o[7] = (short)f2bf(b.w);
    *(bf16x8*)d = o;
}

static __device__ __forceinline__ bf16x8 cvt8r(const float* __restrict__ s) {
    float4 a = *(const float4*)s;
    float4 b = *(const float4*)(s + 4);
    bf16x8 v;
    v[0] = (short)f2bf(a.x); v[1] = (short)f2bf(a.y);
    v[2] = (short)f2bf(a.z); v[3] = (short)f2bf(a.w);
    v[4] = (short)f2bf(b.x); v[5] = (short)f2bf(b.y);
    v[6] = (short)f2bf(b.z); v[7] = (short)f2bf(b.w);
    return v;
}

#define SWZ(r)   (((r) & 7) << 4)
#define SWZ4(r)  ((((r) >> 1) & 3) << 4)

static __device__ __forceinline__ void stage_f32(const float* src, char* base,
                                                 int sr, int sc) {
    *(bf16x8*)(base + ((sr * 64 + sc * 2) ^ SWZ(sr))) = cvt8r(src);
}

// ---------------------------------------------------------------------------
// prep: block-range-dispatched preprocessing (unchanged).
// ---------------------------------------------------------------------------
__global__ __launch_bounds__(256) void prep(
    const int* __restrict__ src, const int* __restrict__ tgt,
    const float* __restrict__ Wc, const float* __restrict__ Wi,
    const float* __restrict__ w_out, const float* __restrict__ w_in,
    const float* __restrict__ bc, const float* __restrict__ bi,
    const float* __restrict__ b_in,
    float* __restrict__ csrc, float* __restrict__ ctgt,
    unsigned short* __restrict__ Wc_bf, unsigned short* __restrict__ wout_bf,
    unsigned short* __restrict__ WcT_bf, unsigned short* __restrict__ Wi_bf,
    unsigned short* __restrict__ wkv_bf, float* __restrict__ beff)
{
    const int bid = blockIdx.x, tid = threadIdx.x;
    if (bid < 32) {
        int e = bid * 256 + tid;
        atomicAdd(&csrc[src[e]], 1.0f);
        atomicAdd(&ctgt[tgt[e]], 1.0f);
    } else if (bid < 64) {
        long i = ((long)(bid - 32) * 256 + tid) * 8;
        cvt8(Wc + i, Wc_bf + i);
    } else if (bid < 96) {
        long i = ((long)(bid - 64) * 256 + tid) * 8;
        cvt8(w_out + i, wout_bf + i);
    } else if (bid < 128) {
        long o = ((long)(bid - 96) * 256 + tid) * 8;
        int c = (int)(o >> 8), d0 = (int)(o & 255);
        bf16x8 v;
#pragma unroll
        for (int j = 0; j < 8; j++) v[j] = (short)f2bf(Wc[(long)(d0 + j) * 256 + c]);
        *(bf16x8*)(WcT_bf + o) = v;
    } else if (bid < 144) {
        long i = ((long)(bid - 128) * 256 + tid) * 8;
        cvt8(Wi + i, Wi_bf + i);
    } else if (bid < 208) {
        long i = ((long)(bid - 144) * 256 + tid) * 8;
        cvt8(w_in + 65536 + i, wkv_bf + i);
    } else {
        int gi = (bid - 208) * 256 + tid;      // [0, 3072)
        int e = gi >> 2, q = gi & 3;
        const float* base = (e < 256) ? bc : bi;
        const float* wr = w_in + (long)e * 256 + q * 64;
        const float* br = base + q * 64;
        float s = 0.f;
#pragma unroll
        for (int j = 0; j < 64; j += 4) {
            float4 w4 = *(const float4*)(wr + j);
            float4 b4 = *(const float4*)(br + j);
            s += w4.x * b4.x + w4.y * b4.y + w4.z * b4.z + w4.w * b4.w;
        }
        s += __shfl_xor(s, 1);
        s += __shfl_xor(s, 2);
        if (q == 0) beff[e] = s + b_in[e];
    }
}

// ---------------------------------------------------------------------------
// fusedW (LDS-staged; unchanged).
// ---------------------------------------------------------------------------
__global__ __launch_bounds__(256) void fusedW(
    const float* __restrict__ w_in, const unsigned short* __restrict__ WcT_bf,
    const float* __restrict__ industry_x, const unsigned short* __restrict__ Wi_bf,
    const unsigned short* __restrict__ wkv_bf, const float* __restrict__ beff,
    const float* __restrict__ ctgt, const float* __restrict__ csrc,
    unsigned short* __restrict__ Wcq_bf, unsigned short* __restrict__ Kbuf,
    unsigned short* __restrict__ VTg,
    float* __restrict__ cntT, int* __restrict__ list, int* __restrict__ nlist)
{
    const int bid = blockIdx.x;
    if (bid >= 20) {
        int i = (bid - 20) * 256 + threadIdx.x;
        if (i < NKEYS) cntT[(i & 15) * 32 + (i >> 4)] = ctgt[i];
        if (i < N_COMP && csrc[i] > 0.f) {
            int k = atomicAdd(nlist, 1);
            list[k] = i;
        }
        return;
    }

    __shared__ char lds[48 * 1024];
    const int t = threadIdx.x, wv = t >> 6, lane = t & 63;
    const int g = lane >> 4, ln = lane & 15;
    const int sr = t >> 2, sc = (t & 3) * 8;

    if (bid < 4) {
        char* ab = lds;
        char* wb = lds + 4 * 1024;
        const int bm = bid * 64;
        f32x4 acc[16];
#pragma unroll
        for (int i = 0; i < 16; i++) acc[i] = (f32x4){0.f, 0.f, 0.f, 0.f};
        const float* aptr = w_in + (long)(bm + sr) * 256 + sc;
        for (int kc = 0; kc < 256; kc += 32) {
            __syncthreads();
            stage_f32(aptr + kc, ab, sr, sc);
#pragma unroll
            for (int p = 0; p < 4; p++) {
                int r = p * 64 + sr;
                *(bf16x8*)(wb + ((r * 64 + sc * 2) ^ SWZ(r))) =
                    *(const bf16x8*)(WcT_bf + (long)r * 256 + kc + sc);
            }
            __syncthreads();
            int ar = wv * 16 + ln;
            bf16x8 af = *(bf16x8*)(ab + ((ar * 64 + g * 16) ^ SWZ(ar)));
#pragma unroll
            for (int nj = 0; nj < 16; nj++) {
                int wr = nj * 16 + ln;
                bf16x8 bf = *(bf16x8*)(wb + ((wr * 64 + g * 16) ^ SWZ(wr)));
                acc[nj] = __builtin_amdgcn_mfma_f32_16x16x32_bf16(af, bf, acc[nj], 0, 0, 0);
            }
        }
#pragma unroll
        for (int nj = 0; nj < 16; nj++)
#pragma unroll
            for (int r = 0; r < 4; r++)
                Wcq_bf[(long)(bm + wv * 16 + g * 4 + r) * 256 + nj * 16 + ln] =
                    f2bf(acc[nj][r]);
        return;
    }

    const int rg = (bid - 4) >> 1, colh = (bid - 4) & 1;
    char* ab  = lds;
    char* wb1 = lds + 4 * 1024;
    char* ihb = lds + 16 * 1024;
    char* wb2 = lds;

    {
        f32x4 a1[16];
#pragma unroll
        for (int i = 0; i < 16; i++) a1[i] = (f32x4){0.f, 0.f, 0.f, 0.f};
        int arow = rg * 64 + sr; if (arow > N_IND - 1) arow = N_IND - 1;
        const float* aptr = industry_x + (long)arow * 128 + sc;
        for (int kc = 0; kc < 128; kc += 32) {
            __syncthreads();
            stage_f32(aptr + kc, ab, sr, sc);
#pragma unroll
            for (int p = 0; p < 4; p++) {
                int r = p * 64 + sr;
                *(bf16x8*)(wb1 + ((r * 64 + sc * 2) ^ SWZ(r))) =
                    *(const bf16x8*)(Wi_bf + (long)r * 128 + kc + sc);
            }
            __syncthreads();
            int ar = wv * 16 + ln;
            bf16x8 af = *(bf16x8*)(ab + ((ar * 64 + g * 16) ^ SWZ(ar)));
#pragma unroll
            for (int nj = 0; nj < 16; nj++) {
                int wr = nj * 16 + ln;
                bf16x8 bf = *(bf16x8*)(wb1 + ((wr * 64 + g * 16) ^ SWZ(wr)));
                a1[nj] = __builtin_amdgcn_mfma_f32_16x16x32_bf16(af, bf, a1[nj], 0, 0, 0);
            }
        }
        __syncthreads();
#pragma unroll
        for (int nj = 0; nj < 16; nj++)
#pragma unroll
            for (int r = 0; r < 4; r++) {
                int row = wv * 16 + g * 4 + r, col = nj * 16 + ln;
                *(unsigned short*)(ihb + ((row * 512 + col * 2) ^ SWZ(row))) =
                    f2bf(a1[nj][r]);
            }
    }
    __syncthreads();

    if (colh == 0) {
        f32x4 a2[16];
#pragma unroll
        for (int i = 0; i < 16; i++) a2[i] = (f32x4){0.f, 0.f, 0.f, 0.f};
        for (int kc = 0; kc < 256; kc += 32) {
            __syncthreads();
#pragma unroll
            for (int p = 0; p < 4; p++) {
                int r = p * 64 + sr;
                *(bf16x8*)(wb2 + ((r * 64 + sc * 2) ^ SWZ(r))) =
                    *(const bf16x8*)(wkv_bf + (long)r * 256 + kc + sc);
            }
            __syncthreads();
            int row = wv * 16 + ln;
            bf16x8 af = *(bf16x8*)(ihb + ((row * 512 + (kc + g * 8) * 2) ^ SWZ(row)));
#pragma unroll
            for (int nj = 0; nj < 16; nj++) {
                int wr = nj * 16 + ln;
                bf16x8 bf = *(bf16x8*)(wb2 + ((wr * 64 + g * 16) ^ SWZ(wr)));
                a2[nj] = __builtin_amdgcn_mfma_f32_16x16x32_bf16(af, bf, a2[nj], 0, 0, 0);
            }
        }
#pragma unroll
        for (int nj = 0; nj < 16; nj++)
#pragma unroll
            for (int r = 0; r < 4; r++) {
                int R = rg * 64 + wv * 16 + g * 4 + r, n = nj * 16 + ln;
                Kbuf[(long)R * 256 + n] = f2bf(a2[nj][r] + beff[256 + n]);
            }
    } else {
        const unsigned short* wp = wkv_bf + 65536;
        f32x4 a2[16];
#pragma unroll
        for (int i = 0; i < 16; i++) a2[i] = (f32x4){0.f, 0.f, 0.f, 0.f};
        for (int kc = 0; kc < 256; kc += 32) {
            __syncthreads();
#pragma unroll
            for (int p = 0; p < 4; p++) {
                int r = p * 64 + sr;
                *(bf16x8*)(wb2 + ((r * 64 + sc * 2) ^ SWZ(r))) =
                    *(const bf16x8*)(wp + (long)r * 256 + kc + sc);
            }
            __syncthreads();
#pragma unroll
            for (int mi = 0; mi < 4; mi++) {
                int arow = wv * 64 + mi * 16 + ln;
                bf16x8 af = *(bf16x8*)(wb2 + ((arow * 64 + g * 16) ^ SWZ(arow)));
#pragma unroll
                for (int t4 = 0; t4 < 4; t4++) {
                    int brow = t4 * 16 + ln;
                    bf16x8 bfr = *(bf16x8*)(ihb + ((brow * 512 + (kc + g * 8) * 2) ^ SWZ(brow)));
                    a2[mi * 4 + t4] = __builtin_amdgcn_mfma_f32_16x16x32_bf16(af, bfr, a2[mi * 4 + t4], 0, 0, 0);
                }
            }
        }
#pragma unroll
        for (int mi = 0; mi < 4; mi++)
#pragma unroll
            for (int t4 = 0; t4 < 4; t4++)
#pragma unroll
                for (int r = 0; r < 4; r++) {
                    int nrow = wv * 64 + mi * 16 + g * 4 + r;
                    VTg[(long)nrow * 512 + rg * 64 + t4 * 16 + ln] =
                        f2bf(a2[mi * 4 + t4][r] + beff[512 + nrow]);
                }
    }
}

// ---------------------------------------------------------------------------
// megattn v7: identical structure to v6 (16 rows/block, 8 waves, k-split),
// but __launch_bounds__(512, 2): 256-VGPR cap so S[8][2] + state stays in
// registers (v6's (512,4) cap forced a 64-VGPR allocation and spilled S to
// scratch: WRITE_SIZE 7 -> 30 MB). Spill gone + 2x wave parallelism vs v5.
// ---------------------------------------------------------------------------
__global__ __launch_bounds__(512, 2) void megattn(
    const float* __restrict__ company_x,
    const unsigned short* __restrict__ Wcq,
    const float* __restrict__ beff,
    const unsigned short* __restrict__ Kbuf,
    const unsigned short* __restrict__ VTg,
    const float* __restrict__ cntT,
    const unsigned short* __restrict__ wout,
    const float* __restrict__ b_out,
    const int* __restrict__ list, const int* __restrict__ nlist,
    float* __restrict__ pooled)
{
    const int M = *nlist;
    const int bm = blockIdx.x * 16;
    if (bm >= M) return;

    __shared__ char lds[57344];
    const int t = threadIdx.x;
    const int w = t >> 6;            // wave 0..7
    const int h = w & 3;             // head
    const int ks = w >> 2;           // key-split half
    const int lane = t & 63, g = lane >> 4, ln = lane & 15;

    char* qbase = lds + h * 2048;              // [16][64] bf16 ctx per head
    char* xbase = lds + 8192;                  // [16][256] bf16
    char* pbase = lds + 16384 + w * 2048;      // wave-private scratch (q-conv + P dbuf)
    float* macc = (float*)(lds + 32768) + h * 1024;  // [16][64] f32 per head
    float* mml  = (float*)(lds + 49152) + h * 512;   // [8][64] f32 per head

    // ---- 1. stage x (512 threads x 8 bf16 = 16x256) ----
    {
        int row = t >> 5, c0 = (t & 31) * 8;
        int mr = bm + row; if (mr > M - 1) mr = M - 1;
        const float* src = company_x + (long)list[mr] * 256 + c0;
        *(bf16x8*)(xbase + ((row * 512 + c0 * 2) ^ SWZ(row))) = cvt8r(src);
    }
    __syncthreads();

    // ---- 2. Q for head h (both ks waves duplicate; wave-private conversion) ----
    bf16x8 qf0, qf1;
    {
        f32x4 qa[4];
#pragma unroll
        for (int i = 0; i < 4; i++) qa[i] = (f32x4){0.f, 0.f, 0.f, 0.f};
#pragma unroll
        for (int kc = 0; kc < 256; kc += 32) {
            bf16x8 af = *(bf16x8*)(xbase + ((ln * 512 + (kc + g * 8) * 2) ^ SWZ(ln)));
#pragma unroll
            for (int nj = 0; nj < 4; nj++) {
                bf16x8 bf = *(const bf16x8*)(Wcq + (long)(h * 64 + nj * 16 + ln) * 256 + kc + g * 8);
                qa[nj] = __builtin_amdgcn_mfma_f32_16x16x32_bf16(af, bf, qa[nj], 0, 0, 0);
            }
        }
#pragma unroll
        for (int nj = 0; nj < 4; nj++)
#pragma unroll
            for (int r = 0; r < 4; r++) {
                int row = g * 4 + r, col = nj * 16 + ln;
                *(unsigned short*)(pbase + ((row * 128 + col * 2) ^ SWZ(row))) =
                    f2bf((qa[nj][r] + beff[h * 64 + col]) * 0.125f);
            }
        qf0 = *(bf16x8*)(pbase + ((ln * 128 + g * 16) ^ SWZ(ln)));
        qf1 = *(bf16x8*)(pbase + ((ln * 128 + 64 + g * 16) ^ SWZ(ln)));
    }

    // ---- 3a. QK^T over this wave's 256 keys (32 independent loads) ----
    f32x4 S[8][2];
#pragma unroll
    for (int c = 0; c < 8; c++)
#pragma unroll
        for (int sub = 0; sub < 2; sub++) {
            const unsigned short* kr =
                Kbuf + (long)(ks * 256 + c * 32 + sub * 16 + ln) * 256 + h * 64 + g * 8;
            bf16x8 k0 = *(const bf16x8*)(kr);
            bf16x8 k1 = *(const bf16x8*)(kr + 32);
            f32x4 s = (f32x4){0.f, 0.f, 0.f, 0.f};
            s = __builtin_amdgcn_mfma_f32_16x16x32_bf16(qf0, k0, s, 0, 0, 0);
            s = __builtin_amdgcn_mfma_f32_16x16x32_bf16(qf1, k1, s, 0, 0, 0);
            S[c][sub] = s;
        }

    // ---- 3b. counts for this half ----
    float cnt[16];
    {
        const float* cp = cntT + ln * 32 + ks * 16;
#pragma unroll
        for (int j4 = 0; j4 < 4; j4++) {
            float4 c4 = *(const float4*)(cp + j4 * 4);
            cnt[j4 * 4 + 0] = c4.x; cnt[j4 * 4 + 1] = c4.y;
            cnt[j4 * 4 + 2] = c4.z; cnt[j4 * 4 + 3] = c4.w;
        }
    }

    // ---- 3c. single-pass softmax over 256 keys ----
    float tm[4] = {-1e30f, -1e30f, -1e30f, -1e30f};
#pragma unroll
    for (int c = 0; c < 8; c++)
#pragma unroll
        for (int sub = 0; sub < 2; sub++)
#pragma unroll
            for (int r = 0; r < 4; r++) tm[r] = fmaxf(tm[r], S[c][sub][r]);
#pragma unroll
    for (int st = 1; st < 16; st <<= 1)
#pragma unroll
        for (int r = 0; r < 4; r++) tm[r] = fmaxf(tm[r], __shfl_xor(tm[r], st));

    float ps[4] = {0.f, 0.f, 0.f, 0.f};
#pragma unroll
    for (int c = 0; c < 8; c++)
#pragma unroll
        for (int sub = 0; sub < 2; sub++) {
            float cv = cnt[c * 2 + sub];
#pragma unroll
            for (int r = 0; r < 4; r++) {
                float p = cv * __expf(S[c][sub][r] - tm[r]);
                S[c][sub][r] = p;
                ps[r] += p;
            }
        }
#pragma unroll
    for (int st = 1; st < 16; st <<= 1)
#pragma unroll
        for (int r = 0; r < 4; r++) ps[r] += __shfl_xor(ps[r], st);

    // ---- 3d. PV over 8 chunks (wave-private double-buffered P LDS) ----
    f32x4 acc[4];
#pragma unroll
    for (int i = 0; i < 4; i++) acc[i] = (f32x4){0.f, 0.f, 0.f, 0.f};
#pragma unroll
    for (int c = 0; c < 8; c++) {
        char* pb = pbase + (c & 1) * 1024;
#pragma unroll
        for (int sub = 0; sub < 2; sub++)
#pragma unroll
            for (int r = 0; r < 4; r++) {
                int row = g * 4 + r;
                *(unsigned short*)(pb + ((row * 64 + (sub * 16 + ln) * 2) ^ SWZ4(row))) =
                    f2bf(S[c][sub][r]);
            }
        bf16x8 pa = *(bf16x8*)(pb + ((ln * 64 + g * 16) ^ SWZ4(ln)));
#pragma unroll
        for (int t4 = 0; t4 < 4; t4++) {
            bf16x8 vf = *(const bf16x8*)(
                VTg + (long)(h * 64 + t4 * 16 + ln) * 512 + ks * 256 + c * 32 + g * 8);
            acc[t4] = __builtin_amdgcn_mfma_f32_16x16x32_bf16(pa, vf, acc[t4], 0, 0, 0);
        }
    }

    // ---- 4. merge the two key-halves per head (exact log-sum-exp) ----
    if (ks == 1) {
#pragma unroll
        for (int t4 = 0; t4 < 4; t4++)
#pragma unroll
            for (int r = 0; r < 4; r++)
                macc[(t4 * 4 + r) * 64 + lane] = acc[t4][r];
#pragma unroll
        for (int r = 0; r < 4; r++) {
            mml[r * 64 + lane] = tm[r];
            mml[(4 + r) * 64 + lane] = ps[r];
        }
    }
    __syncthreads();
    if (ks == 0) {
        float sc0[4], sc1[4];
#pragma unroll
        for (int r = 0; r < 4; r++) {
            float m1 = mml[r * 64 + lane];
            float l1 = mml[(4 + r) * 64 + lane];
            float mn = fmaxf(tm[r], m1);
            float c0 = __expf(tm[r] - mn);
            float c1 = __expf(m1 - mn);
            float inv = 1.0f / (ps[r] * c0 + l1 * c1);
            sc0[r] = c0 * inv;
            sc1[r] = c1 * inv;
        }
#pragma unroll
        for (int t4 = 0; t4 < 4; t4++)
#pragma unroll
            for (int r = 0; r < 4; r++) {
                float ctxv = acc[t4][r] * sc0[r] + macc[(t4 * 4 + r) * 64 + lane] * sc1[r];
                int row = g * 4 + r, col = t4 * 16 + ln;
                *(unsigned short*)(qbase + ((row * 128 + col * 2) ^ SWZ(row))) =
                    f2bf(ctxv);
            }
    }
    __syncthreads();

    // ---- 5. out-proj: wave w handles cols [32w, 32w+32) ----
    {
        f32x4 oa[2];
#pragma unroll
        for (int i = 0; i < 2; i++) oa[i] = (f32x4){0.f, 0.f, 0.f, 0.f};
#pragma unroll
        for (int kc = 0; kc < 256; kc += 32) {
            int hs = kc >> 6;
            int off = (kc & 63) + g * 8;
            bf16x8 af = *(bf16x8*)(lds + hs * 2048 + ((ln * 128 + off * 2) ^ SWZ(ln)));
#pragma unroll
            for (int nj = 0; nj < 2; nj++) {
                int n = w * 32 + nj * 16 + ln;
                bf16x8 bf = *(const bf16x8*)(wout + (long)n * 256 + kc + g * 8);
                oa[nj] = __builtin_amdgcn_mfma_f32_16x16x32_bf16(af, bf, oa[nj], 0, 0, 0);
            }
        }
#pragma unroll
        for (int nj = 0; nj < 2; nj++) {
            int n = w * 32 + nj * 16 + ln;
            float bv = b_out[n];
#pragma unroll
            for (int r = 0; r < 4; r++) {
                int R = bm + g * 4 + r;
                if (R < M)
                    pooled[(long)list[R] * 256 + n] = oa[nj][r] + bv;
            }
        }
    }
}

// ---------------------------------------------------------------------------
// gemm_ln (LDS-staged; unchanged).
// ---------------------------------------------------------------------------
__global__ __launch_bounds__(256) void gemm_ln(
    const float* __restrict__ A, const unsigned short* __restrict__ W,
    const float* __restrict__ bias,
    const float* __restrict__ pooled, const float* __restrict__ csrc,
    const float* __restrict__ gamma, const float* __restrict__ beta,
    float* __restrict__ out, int M, int K)
{
    __shared__ unsigned short As[64 * 32];
    __shared__ unsigned short Ws[256 * 32];
    char* abase = (char*)As;
    char* wbase = (char*)Ws;

    const int bm = blockIdx.x * 64;
    const int t = threadIdx.x;
    const int wv = t >> 6, lane = t & 63, g = lane >> 4, ln = lane & 15;

    f32x4 acc[16];
#pragma unroll
    for (int i = 0; i < 16; i++) acc[i] = (f32x4){0.f, 0.f, 0.f, 0.f};

    const int sr = t >> 2;
    const int sc = (t & 3) * 8;
    int arow = bm + sr; if (arow > M - 1) arow = M - 1;
    const float* aptr = A + (long)arow * K + sc;

    for (int kc = 0; kc < K; kc += 32) {
        __syncthreads();
        stage_f32(aptr + kc, abase, sr, sc);
#pragma unroll
        for (int p = 0; p < 4; p++) {
            int r = p * 64 + sr;
            *(bf16x8*)(wbase + ((r * 64 + sc * 2) ^ SWZ(r))) =
                *(const bf16x8*)(W + (long)r * K + kc + sc);
        }
        __syncthreads();

        const int ar = wv * 16 + ln;
        bf16x8 af = *(bf16x8*)(abase + ((ar * 64 + g * 16) ^ SWZ(ar)));
#pragma unroll
        for (int nj = 0; nj < 16; nj++) {
            int wr = nj * 16 + ln;
            bf16x8 bf = *(bf16x8*)(wbase + ((wr * 64 + g * 16) ^ SWZ(wr)));
            acc[nj] = __builtin_amdgcn_mfma_f32_16x16x32_bf16(af, bf, acc[nj], 0, 0, 0);
        }
    }

#pragma unroll
    for (int r = 0; r < 4; r++) {
        int R = bm + wv * 16 + g * 4 + r;
        bool valid = R < M;
        int Rc = valid ? R : 0;
        float cntv = csrc[Rc];
        float factor = (valid && cntv > 0.f) ? cntv / (cntv + 1e-6f) : 0.f;

        float v[16];
        float sum = 0.f, sq = 0.f;
#pragma unroll
        for (int nj = 0; nj < 16; nj++) {
            int n = nj * 16 + ln;
            float x = acc[nj][r] + bias[n] + factor * pooled[(long)Rc * 256 + n];
            v[nj] = x;
            sum += x;
            sq  += x * x;
        }
#pragma unroll
        for (int st = 1; st < 16; st <<= 1) {
            sum += __shfl_xor(sum, st);
            sq  += __shfl_xor(sq,  st);
        }
        float mean = sum * (1.0f / 256.0f);
        float var  = sq * (1.0f / 256.0f) - mean * mean;
        float rstd = rsqrtf(var + 1e-5f);
        if (valid) {
#pragma unroll
            for (int nj = 0; nj < 16; nj++) {
                int n = nj * 16 + ln;
                out[(long)R * 256 + n] = (v[nj] - mean) * rstd * gamma[n] + beta[n];
            }
        }
    }
}

// ---------------------------------------------------------------------------
extern "C" void kernel_launch(void* const* d_in, const int* in_sizes, int n_in,
                              void* d_out, int out_size, void* d_ws, size_t ws_size,
                              hipStream_t stream)
{
    const float* company_x  = (const float*)d_in[0];
    const float* industry_x = (const float*)d_in[1];
    const int*   edge       = (const int*)d_in[2];
    const float* Wc         = (const float*)d_in[3];
    const float* bc         = (const float*)d_in[4];
    const float* Wi         = (const float*)d_in[5];
    const float* bi         = (const float*)d_in[6];
    const float* w_in       = (const float*)d_in[7];
    const float* b_in       = (const float*)d_in[8];
    const float* w_out      = (const float*)d_in[9];
    const float* b_out      = (const float*)d_in[10];
    const float* gamma      = (const float*)d_in[11];
    const float* beta       = (const float*)d_in[12];
    float* out = (float*)d_out;

    const int* src = edge;
    const int* tgt = edge + E_EDGES;

    // workspace carve (float units)
    float* wf = (float*)d_ws;
    size_t o = 0;
    unsigned short* Wc_bf   = (unsigned short*)(wf + o); o += 32768;  // 256x256
    unsigned short* wout_bf = (unsigned short*)(wf + o); o += 32768;
    unsigned short* WcT_bf  = (unsigned short*)(wf + o); o += 32768;
    unsigned short* Wi_bf   = (unsigned short*)(wf + o); o += 16384;  // 256x128
    unsigned short* wkv_bf  = (unsigned short*)(wf + o); o += 65536;  // 512x256
    unsigned short* Wcq_bf  = (unsigned short*)(wf + o); o += 32768;
    unsigned short* Kbuf    = (unsigned short*)(wf + o); o += 65536;  // 512x256
    unsigned short* VTg     = (unsigned short*)(wf + o); o += 65536;  // 256x512
    float* pooled           = wf + o; o += (size_t)N_COMP * 256;
    float* beff             = wf + o; o += 768;
    float* cntT             = wf + o; o += NKEYS;
    int*   list             = (int*)(wf + o); o += E_EDGES;
    // contiguous zeroed region: csrc | ctgt | nlist
    float* csrc             = wf + o; o += N_COMP;
    float* ctgt             = wf + o; o += NKEYS;
    int*   nlist            = (int*)(wf + o); o += 4;

    hipMemsetAsync(csrc, 0, (N_COMP + NKEYS + 4) * sizeof(float), stream);

    prep<<<dim3(220), dim3(256), 0, stream>>>(
        src, tgt, Wc, Wi, w_out, w_in, bc, bi, b_in,
        csrc, ctgt, Wc_bf, wout_bf, WcT_bf, Wi_bf, wkv_bf, beff);

    fusedW<<<dim3(99), dim3(256), 0, stream>>>(
        w_in, WcT_bf, industry_x, Wi_bf, wkv_bf, beff, ctgt, csrc,
        Wcq_bf, Kbuf, VTg, cntT, list, nlist);

    megattn<<<dim3(E_EDGES / 16), dim3(512), 0, stream>>>(
        company_x, Wcq_bf, beff, Kbuf, VTg, cntT, wout_bf, b_out,
        list, nlist, pooled);

    gemm_ln<<<dim3((N_COMP + 63) / 64), dim3(256), 0, stream>>>(
        company_x, Wc_bf, bc, pooled, csrc, gamma, beta, out, N_COMP, 256);
}

// Round 13
// 102.600 us; speedup vs baseline: 1.1245x; 1.1111x over previous
//
#include <hip/hip_runtime.h>

#define E_EDGES 8192
#define N_COMP  20000
#define N_IND   500
#define NKEYS   512

typedef short bf16x8 __attribute__((ext_vector_type(8)));
typedef float f32x4  __attribute__((ext_vector_type(4)));

static __device__ __forceinline__ unsigned short f2bf(float v) {
    unsigned u = __builtin_bit_cast(unsigned, v);
    u = (u + 0x7FFFu + ((u >> 16) & 1u)) >> 16;
    return (unsigned short)u;
}

static __device__ __forceinline__ void cvt8(const float* __restrict__ s,
                                            unsigned short* __restrict__ d) {
    float4 a = *(const float4*)s;
    float4 b = *(const float4*)(s + 4);
    bf16x8 o;
    o[0] = (short)f2bf(a.x); o[1] = (short)f2bf(a.y);
    o[2] = (short)f2bf(a.z); o[3] = (short)f2bf(a.w);
    o[4] = (short)f2bf(b.x); o[5] = (short)f2bf(b.y);
    o[6] = (short)f2bf(b.z); o[7] = (short)f2bf(b.w);
    *(bf16x8*)d = o;
}

static __device__ __forceinline__ bf16x8 cvt8r(const float* __restrict__ s) {
    float4 a = *(const float4*)s;
    float4 b = *(const float4*)(s + 4);
    bf16x8 v;
    v[0] = (short)f2bf(a.x); v[1] = (short)f2bf(a.y);
    v[2] = (short)f2bf(a.z); v[3] = (short)f2bf(a.w);
    v[4] = (short)f2bf(b.x); v[5] = (short)f2bf(b.y);
    v[6] = (short)f2bf(b.z); v[7] = (short)f2bf(b.w);
    return v;
}

#define SWZ(r)   (((r) & 7) << 4)
#define SWZ4(r)  ((((r) >> 1) & 3) << 4)

static __device__ __forceinline__ void stage_f32(const float* src, char* base,
                                                 int sr, int sc) {
    *(bf16x8*)(base + ((sr * 64 + sc * 2) ^ SWZ(sr))) = cvt8r(src);
}

// ---------------------------------------------------------------------------
// prep: block-range-dispatched preprocessing (unchanged, known-good).
// ---------------------------------------------------------------------------
__global__ __launch_bounds__(256) void prep(
    const int* __restrict__ src, const int* __restrict__ tgt,
    const float* __restrict__ Wc, const float* __restrict__ Wi,
    const float* __restrict__ w_out, const float* __restrict__ w_in,
    const float* __restrict__ bc, const float* __restrict__ bi,
    const float* __restrict__ b_in,
    float* __restrict__ csrc, float* __restrict__ ctgt,
    unsigned short* __restrict__ Wc_bf, unsigned short* __restrict__ wout_bf,
    unsigned short* __restrict__ WcT_bf, unsigned short* __restrict__ Wi_bf,
    unsigned short* __restrict__ wkv_bf, float* __restrict__ beff)
{
    const int bid = blockIdx.x, tid = threadIdx.x;
    if (bid < 32) {
        int e = bid * 256 + tid;
        atomicAdd(&csrc[src[e]], 1.0f);
        atomicAdd(&ctgt[tgt[e]], 1.0f);
    } else if (bid < 64) {
        long i = ((long)(bid - 32) * 256 + tid) * 8;
        cvt8(Wc + i, Wc_bf + i);
    } else if (bid < 96) {
        long i = ((long)(bid - 64) * 256 + tid) * 8;
        cvt8(w_out + i, wout_bf + i);
    } else if (bid < 128) {
        long o = ((long)(bid - 96) * 256 + tid) * 8;
        int c = (int)(o >> 8), d0 = (int)(o & 255);
        bf16x8 v;
#pragma unroll
        for (int j = 0; j < 8; j++) v[j] = (short)f2bf(Wc[(long)(d0 + j) * 256 + c]);
        *(bf16x8*)(WcT_bf + o) = v;
    } else if (bid < 144) {
        long i = ((long)(bid - 128) * 256 + tid) * 8;
        cvt8(Wi + i, Wi_bf + i);
    } else if (bid < 208) {
        long i = ((long)(bid - 144) * 256 + tid) * 8;
        cvt8(w_in + 65536 + i, wkv_bf + i);
    } else {
        int gi = (bid - 208) * 256 + tid;      // [0, 3072)
        int e = gi >> 2, q = gi & 3;
        const float* base = (e < 256) ? bc : bi;
        const float* wr = w_in + (long)e * 256 + q * 64;
        const float* br = base + q * 64;
        float s = 0.f;
#pragma unroll
        for (int j = 0; j < 64; j += 4) {
            float4 w4 = *(const float4*)(wr + j);
            float4 b4 = *(const float4*)(br + j);
            s += w4.x * b4.x + w4.y * b4.y + w4.z * b4.z + w4.w * b4.w;
        }
        s += __shfl_xor(s, 1);
        s += __shfl_xor(s, 2);
        if (q == 0) beff[e] = s + b_in[e];
    }
}

// ---------------------------------------------------------------------------
// fusedW (LDS-staged; unchanged, known-good).
// ---------------------------------------------------------------------------
__global__ __launch_bounds__(256) void fusedW(
    const float* __restrict__ w_in, const unsigned short* __restrict__ WcT_bf,
    const float* __restrict__ industry_x, const unsigned short* __restrict__ Wi_bf,
    const unsigned short* __restrict__ wkv_bf, const float* __restrict__ beff,
    const float* __restrict__ ctgt, const float* __restrict__ csrc,
    unsigned short* __restrict__ Wcq_bf, unsigned short* __restrict__ Kbuf,
    unsigned short* __restrict__ VTg,
    float* __restrict__ cntT, int* __restrict__ list, int* __restrict__ nlist)
{
    const int bid = blockIdx.x;
    if (bid >= 20) {
        int i = (bid - 20) * 256 + threadIdx.x;
        if (i < NKEYS) cntT[(i & 15) * 32 + (i >> 4)] = ctgt[i];
        if (i < N_COMP && csrc[i] > 0.f) {
            int k = atomicAdd(nlist, 1);
            list[k] = i;
        }
        return;
    }

    __shared__ char lds[48 * 1024];
    const int t = threadIdx.x, wv = t >> 6, lane = t & 63;
    const int g = lane >> 4, ln = lane & 15;
    const int sr = t >> 2, sc = (t & 3) * 8;

    if (bid < 4) {
        char* ab = lds;
        char* wb = lds + 4 * 1024;
        const int bm = bid * 64;
        f32x4 acc[16];
#pragma unroll
        for (int i = 0; i < 16; i++) acc[i] = (f32x4){0.f, 0.f, 0.f, 0.f};
        const float* aptr = w_in + (long)(bm + sr) * 256 + sc;
        for (int kc = 0; kc < 256; kc += 32) {
            __syncthreads();
            stage_f32(aptr + kc, ab, sr, sc);
#pragma unroll
            for (int p = 0; p < 4; p++) {
                int r = p * 64 + sr;
                *(bf16x8*)(wb + ((r * 64 + sc * 2) ^ SWZ(r))) =
                    *(const bf16x8*)(WcT_bf + (long)r * 256 + kc + sc);
            }
            __syncthreads();
            int ar = wv * 16 + ln;
            bf16x8 af = *(bf16x8*)(ab + ((ar * 64 + g * 16) ^ SWZ(ar)));
#pragma unroll
            for (int nj = 0; nj < 16; nj++) {
                int wr = nj * 16 + ln;
                bf16x8 bf = *(bf16x8*)(wb + ((wr * 64 + g * 16) ^ SWZ(wr)));
                acc[nj] = __builtin_amdgcn_mfma_f32_16x16x32_bf16(af, bf, acc[nj], 0, 0, 0);
            }
        }
#pragma unroll
        for (int nj = 0; nj < 16; nj++)
#pragma unroll
            for (int r = 0; r < 4; r++)
                Wcq_bf[(long)(bm + wv * 16 + g * 4 + r) * 256 + nj * 16 + ln] =
                    f2bf(acc[nj][r]);
        return;
    }

    const int rg = (bid - 4) >> 1, colh = (bid - 4) & 1;
    char* ab  = lds;
    char* wb1 = lds + 4 * 1024;
    char* ihb = lds + 16 * 1024;
    char* wb2 = lds;

    {
        f32x4 a1[16];
#pragma unroll
        for (int i = 0; i < 16; i++) a1[i] = (f32x4){0.f, 0.f, 0.f, 0.f};
        int arow = rg * 64 + sr; if (arow > N_IND - 1) arow = N_IND - 1;
        const float* aptr = industry_x + (long)arow * 128 + sc;
        for (int kc = 0; kc < 128; kc += 32) {
            __syncthreads();
            stage_f32(aptr + kc, ab, sr, sc);
#pragma unroll
            for (int p = 0; p < 4; p++) {
                int r = p * 64 + sr;
                *(bf16x8*)(wb1 + ((r * 64 + sc * 2) ^ SWZ(r))) =
                    *(const bf16x8*)(Wi_bf + (long)r * 128 + kc + sc);
            }
            __syncthreads();
            int ar = wv * 16 + ln;
            bf16x8 af = *(bf16x8*)(ab + ((ar * 64 + g * 16) ^ SWZ(ar)));
#pragma unroll
            for (int nj = 0; nj < 16; nj++) {
                int wr = nj * 16 + ln;
                bf16x8 bf = *(bf16x8*)(wb1 + ((wr * 64 + g * 16) ^ SWZ(wr)));
                a1[nj] = __builtin_amdgcn_mfma_f32_16x16x32_bf16(af, bf, a1[nj], 0, 0, 0);
            }
        }
        __syncthreads();
#pragma unroll
        for (int nj = 0; nj < 16; nj++)
#pragma unroll
            for (int r = 0; r < 4; r++) {
                int row = wv * 16 + g * 4 + r, col = nj * 16 + ln;
                *(unsigned short*)(ihb + ((row * 512 + col * 2) ^ SWZ(row))) =
                    f2bf(a1[nj][r]);
            }
    }
    __syncthreads();

    if (colh == 0) {
        f32x4 a2[16];
#pragma unroll
        for (int i = 0; i < 16; i++) a2[i] = (f32x4){0.f, 0.f, 0.f, 0.f};
        for (int kc = 0; kc < 256; kc += 32) {
            __syncthreads();
#pragma unroll
            for (int p = 0; p < 4; p++) {
                int r = p * 64 + sr;
                *(bf16x8*)(wb2 + ((r * 64 + sc * 2) ^ SWZ(r))) =
                    *(const bf16x8*)(wkv_bf + (long)r * 256 + kc + sc);
            }
            __syncthreads();
            int row = wv * 16 + ln;
            bf16x8 af = *(bf16x8*)(ihb + ((row * 512 + (kc + g * 8) * 2) ^ SWZ(row)));
#pragma unroll
            for (int nj = 0; nj < 16; nj++) {
                int wr = nj * 16 + ln;
                bf16x8 bf = *(bf16x8*)(wb2 + ((wr * 64 + g * 16) ^ SWZ(wr)));
                a2[nj] = __builtin_amdgcn_mfma_f32_16x16x32_bf16(af, bf, a2[nj], 0, 0, 0);
            }
        }
#pragma unroll
        for (int nj = 0; nj < 16; nj++)
#pragma unroll
            for (int r = 0; r < 4; r++) {
                int R = rg * 64 + wv * 16 + g * 4 + r, n = nj * 16 + ln;
                Kbuf[(long)R * 256 + n] = f2bf(a2[nj][r] + beff[256 + n]);
            }
    } else {
        const unsigned short* wp = wkv_bf + 65536;
        f32x4 a2[16];
#pragma unroll
        for (int i = 0; i < 16; i++) a2[i] = (f32x4){0.f, 0.f, 0.f, 0.f};
        for (int kc = 0; kc < 256; kc += 32) {
            __syncthreads();
#pragma unroll
            for (int p = 0; p < 4; p++) {
                int r = p * 64 + sr;
                *(bf16x8*)(wb2 + ((r * 64 + sc * 2) ^ SWZ(r))) =
                    *(const bf16x8*)(wp + (long)r * 256 + kc + sc);
            }
            __syncthreads();
#pragma unroll
            for (int mi = 0; mi < 4; mi++) {
                int arow = wv * 64 + mi * 16 + ln;
                bf16x8 af = *(bf16x8*)(wb2 + ((arow * 64 + g * 16) ^ SWZ(arow)));
#pragma unroll
                for (int t4 = 0; t4 < 4; t4++) {
                    int brow = t4 * 16 + ln;
                    bf16x8 bfr = *(bf16x8*)(ihb + ((brow * 512 + (kc + g * 8) * 2) ^ SWZ(brow)));
                    a2[mi * 4 + t4] = __builtin_amdgcn_mfma_f32_16x16x32_bf16(af, bfr, a2[mi * 4 + t4], 0, 0, 0);
                }
            }
        }
#pragma unroll
        for (int mi = 0; mi < 4; mi++)
#pragma unroll
            for (int t4 = 0; t4 < 4; t4++)
#pragma unroll
                for (int r = 0; r < 4; r++) {
                    int nrow = wv * 64 + mi * 16 + g * 4 + r;
                    VTg[(long)nrow * 512 + rg * 64 + t4 * 16 + ln] =
                        f2bf(a2[mi * 4 + t4][r] + beff[512 + nrow]);
                }
    }
}

// ---------------------------------------------------------------------------
// megattn v8: r10-v5 structure (16 rows/block, 4 waves, wave=head, 2 tiles of
// 256 keys) + forced memory-level parallelism:
//  - QK K-loads in named register groups of 16 (64 VGPRs of dests in flight)
//  - VT loads double-buffered in groups of 8, first group issued BEFORE the
//    softmax so its latency hides under the VALU work
//  - cnt loads hoisted to tile start
//  - P relayout via 4-slot wave-private LDS (no 2-slot reuse stalls)
// ---------------------------------------------------------------------------
__global__ __launch_bounds__(256, 2) void megattn(
    const float* __restrict__ company_x,
    const unsigned short* __restrict__ Wcq,
    const float* __restrict__ beff,
    const unsigned short* __restrict__ Kbuf,
    const unsigned short* __restrict__ VTg,
    const float* __restrict__ cntT,
    const unsigned short* __restrict__ wout,
    const float* __restrict__ b_out,
    const int* __restrict__ list, const int* __restrict__ nlist,
    float* __restrict__ pooled)
{
    const int M = *nlist;
    const int bm = blockIdx.x * 16;
    if (bm >= M) return;

    __shared__ char lds[32768];
    const int t = threadIdx.x, h = t >> 6, lane = t & 63;
    const int g = lane >> 4, ln = lane & 15;
    char* qbase = lds + h * 2048;            // per-wave ctx/q [16][64] bf16
    char* xbase = lds + 8192;                // [16][256] bf16 (Q phase only)
    char* pbase = lds + 16384 + h * 4096;    // per-wave P 4-slot buffer

    // ---- 1. stage x ----
    {
        int row = t >> 4, c0 = (t & 15) * 16;
        int mr = bm + row; if (mr > M - 1) mr = M - 1;
        const float* src = company_x + (long)list[mr] * 256 + c0;
        *(bf16x8*)(xbase + ((row * 512 + c0 * 2) ^ SWZ(row))) = cvt8r(src);
        *(bf16x8*)(xbase + ((row * 512 + c0 * 2 + 16) ^ SWZ(row))) = cvt8r(src + 8);
    }
    __syncthreads();

    // ---- 2. Q (per wave) ----
    bf16x8 qf0, qf1;
    {
        f32x4 qa[4];
#pragma unroll
        for (int i = 0; i < 4; i++) qa[i] = (f32x4){0.f, 0.f, 0.f, 0.f};
#pragma unroll
        for (int kc = 0; kc < 256; kc += 32) {
            bf16x8 af = *(bf16x8*)(xbase + ((ln * 512 + (kc + g * 8) * 2) ^ SWZ(ln)));
#pragma unroll
            for (int nj = 0; nj < 4; nj++) {
                bf16x8 bf = *(const bf16x8*)(Wcq + (long)(h * 64 + nj * 16 + ln) * 256 + kc + g * 8);
                qa[nj] = __builtin_amdgcn_mfma_f32_16x16x32_bf16(af, bf, qa[nj], 0, 0, 0);
            }
        }
#pragma unroll
        for (int nj = 0; nj < 4; nj++)
#pragma unroll
            for (int r = 0; r < 4; r++) {
                int row = g * 4 + r, col = nj * 16 + ln;
                *(unsigned short*)(qbase + ((row * 128 + col * 2) ^ SWZ(row))) =
                    f2bf((qa[nj][r] + beff[h * 64 + col]) * 0.125f);
            }
        qf0 = *(bf16x8*)(qbase + ((ln * 128 + g * 16) ^ SWZ(ln)));
        qf1 = *(bf16x8*)(qbase + ((ln * 128 + 64 + g * 16) ^ SWZ(ln)));
    }

    // ---- 3. flash attention, 2 tiles x 256 keys ----
    f32x4 acc[4];
#pragma unroll
    for (int i = 0; i < 4; i++) acc[i] = (f32x4){0.f, 0.f, 0.f, 0.f};
    float mreg[4] = {-1e30f, -1e30f, -1e30f, -1e30f};
    float lreg[4] = {0.f, 0.f, 0.f, 0.f};

#pragma unroll
    for (int tile = 0; tile < 2; tile++) {
        // counts (independent; issue first so they're in flight during QK)
        float cnt[16];
        {
            const float* cp = cntT + ln * 32 + tile * 16;
#pragma unroll
            for (int j4 = 0; j4 < 4; j4++) {
                float4 c4 = *(const float4*)(cp + j4 * 4);
                cnt[j4 * 4 + 0] = c4.x; cnt[j4 * 4 + 1] = c4.y;
                cnt[j4 * 4 + 2] = c4.z; cnt[j4 * 4 + 3] = c4.w;
            }
        }

        // QK^T: 2 halves, each = 16 grouped loads then 16 MFMA pairs
        f32x4 S[8][2];
#pragma unroll
        for (int half = 0; half < 2; half++) {
            bf16x8 k0r[4][2], k1r[4][2];
#pragma unroll
            for (int c4 = 0; c4 < 4; c4++)
#pragma unroll
                for (int sub = 0; sub < 2; sub++) {
                    const unsigned short* kr = Kbuf +
                        (long)(tile * 256 + (half * 4 + c4) * 32 + sub * 16 + ln) * 256 + h * 64 + g * 8;
                    k0r[c4][sub] = *(const bf16x8*)(kr);
                    k1r[c4][sub] = *(const bf16x8*)(kr + 32);
                }
#pragma unroll
            for (int c4 = 0; c4 < 4; c4++)
#pragma unroll
                for (int sub = 0; sub < 2; sub++) {
                    f32x4 s = (f32x4){0.f, 0.f, 0.f, 0.f};
                    s = __builtin_amdgcn_mfma_f32_16x16x32_bf16(qf0, k0r[c4][sub], s, 0, 0, 0);
                    s = __builtin_amdgcn_mfma_f32_16x16x32_bf16(qf1, k1r[c4][sub], s, 0, 0, 0);
                    S[half * 4 + c4][sub] = s;
                }
        }

        // prefetch VT for chunks 0-1 BEFORE softmax (hides under VALU work)
        bf16x8 vr[2][2][4];
#pragma unroll
        for (int j = 0; j < 2; j++)
#pragma unroll
            for (int t4 = 0; t4 < 4; t4++)
                vr[0][j][t4] = *(const bf16x8*)(
                    VTg + (long)(h * 64 + t4 * 16 + ln) * 512 + tile * 256 + j * 32 + g * 8);

        // tile max + online merge
        float tm[4] = {-1e30f, -1e30f, -1e30f, -1e30f};
#pragma unroll
        for (int c = 0; c < 8; c++)
#pragma unroll
            for (int sub = 0; sub < 2; sub++)
#pragma unroll
                for (int r = 0; r < 4; r++) tm[r] = fmaxf(tm[r], S[c][sub][r]);
#pragma unroll
        for (int st = 1; st < 16; st <<= 1)
#pragma unroll
            for (int r = 0; r < 4; r++) tm[r] = fmaxf(tm[r], __shfl_xor(tm[r], st));

        float corr[4];
#pragma unroll
        for (int r = 0; r < 4; r++) {
            float mn = fmaxf(mreg[r], tm[r]);
            corr[r] = __expf(mreg[r] - mn);
            mreg[r] = mn;
        }

        float ps[4] = {0.f, 0.f, 0.f, 0.f};
#pragma unroll
        for (int c = 0; c < 8; c++)
#pragma unroll
            for (int sub = 0; sub < 2; sub++) {
                float cv = cnt[c * 2 + sub];
#pragma unroll
                for (int r = 0; r < 4; r++) {
                    float p = cv * __expf(S[c][sub][r] - mreg[r]);
                    S[c][sub][r] = p;
                    ps[r] += p;
                }
            }
#pragma unroll
        for (int st = 1; st < 16; st <<= 1)
#pragma unroll
            for (int r = 0; r < 4; r++) ps[r] += __shfl_xor(ps[r], st);
#pragma unroll
        for (int r = 0; r < 4; r++) lreg[r] = lreg[r] * corr[r] + ps[r];
#pragma unroll
        for (int i = 0; i < 4; i++)
#pragma unroll
            for (int r = 0; r < 4; r++) acc[i][r] *= corr[r];

        // PV: 4 groups of 2 chunks; prefetch group grp+1 while computing grp
#pragma unroll
        for (int grp = 0; grp < 4; grp++) {
            if (grp < 3) {
#pragma unroll
                for (int j = 0; j < 2; j++)
#pragma unroll
                    for (int t4 = 0; t4 < 4; t4++)
                        vr[(grp + 1) & 1][j][t4] = *(const bf16x8*)(
                            VTg + (long)(h * 64 + t4 * 16 + ln) * 512 +
                            tile * 256 + ((grp + 1) * 2 + j) * 32 + g * 8);
            }
#pragma unroll
            for (int j = 0; j < 2; j++) {
                int c = grp * 2 + j;
                char* pb = pbase + (c & 3) * 1024;
#pragma unroll
                for (int sub = 0; sub < 2; sub++)
#pragma unroll
                    for (int r = 0; r < 4; r++) {
                        int row = g * 4 + r;
                        *(unsigned short*)(pb + ((row * 64 + (sub * 16 + ln) * 2) ^ SWZ4(row))) =
                            f2bf(S[c][sub][r]);
                    }
                bf16x8 pa = *(bf16x8*)(pb + ((ln * 64 + g * 16) ^ SWZ4(ln)));
#pragma unroll
                for (int t4 = 0; t4 < 4; t4++)
                    acc[t4] = __builtin_amdgcn_mfma_f32_16x16x32_bf16(
                        pa, vr[grp & 1][j][t4], acc[t4], 0, 0, 0);
            }
        }
    }

    // ---- 4. ctx_h -> own q slot ----
#pragma unroll
    for (int t4 = 0; t4 < 4; t4++)
#pragma unroll
        for (int r = 0; r < 4; r++) {
            int row = g * 4 + r, col = t4 * 16 + ln;
            *(unsigned short*)(qbase + ((row * 128 + col * 2) ^ SWZ(row))) =
                f2bf(acc[t4][r] / lreg[r]);
        }
    __syncthreads();

    // ---- 5. out-proj cols [64h, 64h+64) -> pooled ----
    {
        f32x4 oa[4];
#pragma unroll
        for (int i = 0; i < 4; i++) oa[i] = (f32x4){0.f, 0.f, 0.f, 0.f};
#pragma unroll
        for (int kc = 0; kc < 256; kc += 32) {
            int hs = kc >> 6;
            int off = (kc & 63) + g * 8;
            bf16x8 af = *(bf16x8*)(lds + hs * 2048 + ((ln * 128 + off * 2) ^ SWZ(ln)));
#pragma unroll
            for (int nj = 0; nj < 4; nj++) {
                bf16x8 bf = *(const bf16x8*)(wout + (long)(h * 64 + nj * 16 + ln) * 256 + kc + g * 8);
                oa[nj] = __builtin_amdgcn_mfma_f32_16x16x32_bf16(af, bf, oa[nj], 0, 0, 0);
            }
        }
#pragma unroll
        for (int nj = 0; nj < 4; nj++) {
            int n = h * 64 + nj * 16 + ln;
            float bv = b_out[n];
#pragma unroll
            for (int r = 0; r < 4; r++) {
                int R = bm + g * 4 + r;
                if (R < M)
                    pooled[(long)list[R] * 256 + n] = oa[nj][r] + bv;
            }
        }
    }
}

// ---------------------------------------------------------------------------
// gemm_ln (LDS-staged; unchanged, known-good).
// ---------------------------------------------------------------------------
__global__ __launch_bounds__(256) void gemm_ln(
    const float* __restrict__ A, const unsigned short* __restrict__ W,
    const float* __restrict__ bias,
    const float* __restrict__ pooled, const float* __restrict__ csrc,
    const float* __restrict__ gamma, const float* __restrict__ beta,
    float* __restrict__ out, int M, int K)
{
    __shared__ unsigned short As[64 * 32];
    __shared__ unsigned short Ws[256 * 32];
    char* abase = (char*)As;
    char* wbase = (char*)Ws;

    const int bm = blockIdx.x * 64;
    const int t = threadIdx.x;
    const int wv = t >> 6, lane = t & 63, g = lane >> 4, ln = lane & 15;

    f32x4 acc[16];
#pragma unroll
    for (int i = 0; i < 16; i++) acc[i] = (f32x4){0.f, 0.f, 0.f, 0.f};

    const int sr = t >> 2;
    const int sc = (t & 3) * 8;
    int arow = bm + sr; if (arow > M - 1) arow = M - 1;
    const float* aptr = A + (long)arow * K + sc;

    for (int kc = 0; kc < K; kc += 32) {
        __syncthreads();
        stage_f32(aptr + kc, abase, sr, sc);
#pragma unroll
        for (int p = 0; p < 4; p++) {
            int r = p * 64 + sr;
            *(bf16x8*)(wbase + ((r * 64 + sc * 2) ^ SWZ(r))) =
                *(const bf16x8*)(W + (long)r * K + kc + sc);
        }
        __syncthreads();

        const int ar = wv * 16 + ln;
        bf16x8 af = *(bf16x8*)(abase + ((ar * 64 + g * 16) ^ SWZ(ar)));
#pragma unroll
        for (int nj = 0; nj < 16; nj++) {
            int wr = nj * 16 + ln;
            bf16x8 bf = *(bf16x8*)(wbase + ((wr * 64 + g * 16) ^ SWZ(wr)));
            acc[nj] = __builtin_amdgcn_mfma_f32_16x16x32_bf16(af, bf, acc[nj], 0, 0, 0);
        }
    }

#pragma unroll
    for (int r = 0; r < 4; r++) {
        int R = bm + wv * 16 + g * 4 + r;
        bool valid = R < M;
        int Rc = valid ? R : 0;
        float cntv = csrc[Rc];
        float factor = (valid && cntv > 0.f) ? cntv / (cntv + 1e-6f) : 0.f;

        float v[16];
        float sum = 0.f, sq = 0.f;
#pragma unroll
        for (int nj = 0; nj < 16; nj++) {
            int n = nj * 16 + ln;
            float x = acc[nj][r] + bias[n] + factor * pooled[(long)Rc * 256 + n];
            v[nj] = x;
            sum += x;
            sq  += x * x;
        }
#pragma unroll
        for (int st = 1; st < 16; st <<= 1) {
            sum += __shfl_xor(sum, st);
            sq  += __shfl_xor(sq,  st);
        }
        float mean = sum * (1.0f / 256.0f);
        float var  = sq * (1.0f / 256.0f) - mean * mean;
        float rstd = rsqrtf(var + 1e-5f);
        if (valid) {
#pragma unroll
            for (int nj = 0; nj < 16; nj++) {
                int n = nj * 16 + ln;
                out[(long)R * 256 + n] = (v[nj] - mean) * rstd * gamma[n] + beta[n];
            }
        }
    }
}

// ---------------------------------------------------------------------------
extern "C" void kernel_launch(void* const* d_in, const int* in_sizes, int n_in,
                              void* d_out, int out_size, void* d_ws, size_t ws_size,
                              hipStream_t stream)
{
    const float* company_x  = (const float*)d_in[0];
    const float* industry_x = (const float*)d_in[1];
    const int*   edge       = (const int*)d_in[2];
    const float* Wc         = (const float*)d_in[3];
    const float* bc         = (const float*)d_in[4];
    const float* Wi         = (const float*)d_in[5];
    const float* bi         = (const float*)d_in[6];
    const float* w_in       = (const float*)d_in[7];
    const float* b_in       = (const float*)d_in[8];
    const float* w_out      = (const float*)d_in[9];
    const float* b_out      = (const float*)d_in[10];
    const float* gamma      = (const float*)d_in[11];
    const float* beta       = (const float*)d_in[12];
    float* out = (float*)d_out;

    const int* src = edge;
    const int* tgt = edge + E_EDGES;

    // workspace carve (float units)
    float* wf = (float*)d_ws;
    size_t o = 0;
    unsigned short* Wc_bf   = (unsigned short*)(wf + o); o += 32768;  // 256x256
    unsigned short* wout_bf = (unsigned short*)(wf + o); o += 32768;
    unsigned short* WcT_bf  = (unsigned short*)(wf + o); o += 32768;
    unsigned short* Wi_bf   = (unsigned short*)(wf + o); o += 16384;  // 256x128
    unsigned short* wkv_bf  = (unsigned short*)(wf + o); o += 65536;  // 512x256
    unsigned short* Wcq_bf  = (unsigned short*)(wf + o); o += 32768;
    unsigned short* Kbuf    = (unsigned short*)(wf + o); o += 65536;  // 512x256
    unsigned short* VTg     = (unsigned short*)(wf + o); o += 65536;  // 256x512
    float* pooled           = wf + o; o += (size_t)N_COMP * 256;
    float* beff             = wf + o; o += 768;
    float* cntT             = wf + o; o += NKEYS;
    int*   list             = (int*)(wf + o); o += E_EDGES;
    // contiguous zeroed region: csrc | ctgt | nlist
    float* csrc             = wf + o; o += N_COMP;
    float* ctgt             = wf + o; o += NKEYS;
    int*   nlist            = (int*)(wf + o); o += 4;

    hipMemsetAsync(csrc, 0, (N_COMP + NKEYS + 4) * sizeof(float), stream);

    prep<<<dim3(220), dim3(256), 0, stream>>>(
        src, tgt, Wc, Wi, w_out, w_in, bc, bi, b_in,
        csrc, ctgt, Wc_bf, wout_bf, WcT_bf, Wi_bf, wkv_bf, beff);

    fusedW<<<dim3(99), dim3(256), 0, stream>>>(
        w_in, WcT_bf, industry_x, Wi_bf, wkv_bf, beff, ctgt, csrc,
        Wcq_bf, Kbuf, VTg, cntT, list, nlist);

    megattn<<<dim3(E_EDGES / 16), dim3(256), 0, stream>>>(
        company_x, Wcq_bf, beff, Kbuf, VTg, cntT, wout_bf, b_out,
        list, nlist, pooled);

    gemm_ln<<<dim3((N_COMP + 63) / 64), dim3(256), 0, stream>>>(
        company_x, Wc_bf, bc, pooled, csrc, gamma, beta, out, N_COMP, 256);
}